// Round 7
// baseline (446.488 us; speedup 1.0000x reference)
//
#include <hip/hip_runtime.h>
#include <math.h>

#define NN 50000
#define FF 128
#define DD 64
#define EE 800000
#define GG 64
#define NEG_SLOPE 0.2f
#define EPSV 1e-16f

// CSR-build bucketing: coarse bucket = dst>>8 (256 nodes each)
#define NBKT 196                     // ceil(NN/256)
#define BCAP 5120                    // max edges/bucket (mean 4096)
#define CHUNK 2048
#define NCH ((EE + CHUNK - 1) / CHUNK)   // 391

// ---------------- CSR build (LDS counting sort) ----------------

__global__ __launch_bounds__(256) void bin_k(const int* __restrict__ src,
                                             const int* __restrict__ dst,
                                             unsigned int* __restrict__ gbuf,
                                             int* __restrict__ gcur) {
    __shared__ unsigned int staged[CHUNK];
    __shared__ int bcnt[256], bstart[256], runbase[256];
    int tid = threadIdx.x;
    bcnt[tid] = 0;
    __syncthreads();
    int base = blockIdx.x * CHUNK;
    int cnt = min(CHUNK, EE - base);
    unsigned int pe[8];
    int bk[8], lofs[8];
#pragma unroll
    for (int k = 0; k < 8; ++k) {
        int i = tid + k * 256;
        bk[k] = -1;
        if (i < cnt) {
            unsigned int s = (unsigned int)src[base + i];
            unsigned int d = (unsigned int)dst[base + i];
            pe[k] = (s << 16) | d;
            bk[k] = (int)(d >> 8);
            lofs[k] = atomicAdd(&bcnt[bk[k]], 1);
        }
    }
    __syncthreads();
    int v = bcnt[tid];
    bstart[tid] = v;
    __syncthreads();
    for (int off = 1; off < 256; off <<= 1) {
        int t = (tid >= off) ? bstart[tid - off] : 0;
        __syncthreads();
        bstart[tid] += t;
        __syncthreads();
    }
    int excl = bstart[tid] - v;
    __syncthreads();
    bstart[tid] = excl;
    __syncthreads();
#pragma unroll
    for (int k = 0; k < 8; ++k)
        if (bk[k] >= 0) staged[bstart[bk[k]] + lofs[k]] = pe[k];
    runbase[tid] = atomicAdd(&gcur[tid], bcnt[tid]);
    __syncthreads();
    for (int i = tid; i < cnt; i += 256) {
        unsigned int p = staged[i];
        int b = (int)((p & 0xFFFFu) >> 8);
        gbuf[(size_t)b * BCAP + runbase[b] + (i - bstart[b])] = p;
    }
}

__global__ __launch_bounds__(256) void bhist_k(const unsigned int* __restrict__ gbuf,
                                               const int* __restrict__ gcur,
                                               int* __restrict__ counts) {
    __shared__ int c2[256];
    int tid = threadIdx.x, b = blockIdx.x;
    c2[tid] = 0;
    __syncthreads();
    int nb = gcur[b];
    const unsigned int* bb = gbuf + (size_t)b * BCAP;
    for (int i = tid; i < nb; i += 256)
        atomicAdd(&c2[bb[i] & 255u], 1);
    __syncthreads();
    int node = b * 256 + tid;
    if (node < NN) counts[node] = c2[tid];
}

#define SCAN_B 256

__global__ void scan1_k(const int* __restrict__ in, int* __restrict__ out,
                        int* __restrict__ bsum, int n) {
    __shared__ int s[SCAN_B];
    int gid = blockIdx.x * SCAN_B + threadIdx.x;
    int v = (gid < n) ? in[gid] : 0;
    s[threadIdx.x] = v;
    __syncthreads();
    for (int off = 1; off < SCAN_B; off <<= 1) {
        int t = (threadIdx.x >= off) ? s[threadIdx.x - off] : 0;
        __syncthreads();
        s[threadIdx.x] += t;
        __syncthreads();
    }
    if (gid < n) out[gid] = s[threadIdx.x] - v;
    if (threadIdx.x == SCAN_B - 1) bsum[blockIdx.x] = s[threadIdx.x];
}

__global__ void scan2_k(int* bsum, int nb) {
    __shared__ int s[SCAN_B];
    int v = (threadIdx.x < nb) ? bsum[threadIdx.x] : 0;
    s[threadIdx.x] = v;
    __syncthreads();
    for (int off = 1; off < SCAN_B; off <<= 1) {
        int t = (threadIdx.x >= off) ? s[threadIdx.x - off] : 0;
        __syncthreads();
        s[threadIdx.x] += t;
        __syncthreads();
    }
    if (threadIdx.x < nb) bsum[threadIdx.x] = s[threadIdx.x] - v;
}

__global__ void scan3_k(int* __restrict__ rowstart, const int* __restrict__ bsum, int n) {
    int gid = blockIdx.x * SCAN_B + threadIdx.x;
    if (gid < n) rowstart[gid] += bsum[blockIdx.x];
    if (gid == 0) rowstart[n] = EE;
}

__global__ __launch_bounds__(256) void place_k(const unsigned int* __restrict__ gbuf,
                                               const int* __restrict__ gcur,
                                               const int* __restrict__ rowstart,
                                               int* __restrict__ csr) {
    __shared__ int rs[256];
    __shared__ int cur[256];
    int tid = threadIdx.x, b = blockIdx.x;
    int node = b * 256 + tid;
    rs[tid] = (node < NN) ? rowstart[node] : 0;
    cur[tid] = 0;
    __syncthreads();
    int nb = gcur[b];
    const unsigned int* bb = gbuf + (size_t)b * BCAP;
    for (int i = tid; i < nb; i += 256) {
        unsigned int p = bb[i];
        int l = (int)(p & 255u);
        int pos = rs[l] + atomicAdd(&cur[l], 1);
        csr[pos] = (int)(p >> 16);
    }
}

// ---------------- per-layer kernels ----------------

// per layer: wdad[k] = Wd[k,:].ad ; wsas[k] = Ws[k,:].as  (es/ed refactor)
__global__ void vecs3_k(const float* __restrict__ Wd0, const float* __restrict__ ad0,
                        const float* __restrict__ Ws0, const float* __restrict__ as0,
                        const float* __restrict__ Wd1, const float* __restrict__ ad1,
                        const float* __restrict__ Ws1, const float* __restrict__ as1,
                        const float* __restrict__ Wd2, const float* __restrict__ ad2,
                        const float* __restrict__ Ws2, const float* __restrict__ as2,
                        float* __restrict__ wdadAll, float* __restrict__ wsasAll) {
    int b = blockIdx.x;
    const float* Wd = (b == 0) ? Wd0 : (b == 1) ? Wd1 : Wd2;
    const float* ad = (b == 0) ? ad0 : (b == 1) ? ad1 : ad2;
    const float* Ws = (b == 0) ? Ws0 : (b == 1) ? Ws1 : Ws2;
    const float* as = (b == 0) ? as0 : (b == 1) ? as1 : as2;
    int Din = (b == 0) ? FF : DD;
    int k = threadIdx.x;
    if (k < Din) {
        float accd = 0.f, accs = 0.f;
        for (int d2 = 0; d2 < DD; ++d2) {
            accd += Wd[k * DD + d2] * ad[d2];
            accs += Ws[k * DD + d2] * as[d2];
        }
        wdadAll[b * FF + k] = accd;
        wsasAll[b * FF + k] = accs;
    }
}

// xs = h @ Ws ; es = h @ (Ws@a_s) ; ed = h @ (Wd@a_d)
// lane = row (64 rows/block), wave = 16-col slice. h per-lane from padded LDS
// (1 ds_read_b128 per 4k); Ws/wsas/wdad wave-uniform -> scalar pipe.
template <int DIN>
__global__ __launch_bounds__(256, 4) void xform_k(
    const float* __restrict__ h, const float* __restrict__ Ws,
    const float* __restrict__ wsas, const float* __restrict__ wdad,
    float* __restrict__ xs, float* __restrict__ es, float* __restrict__ ed,
    int n) {
    constexpr int PAD = DIN + 4;            // 132 / 68: b128-aligned, max-rate banks
    constexpr int XP = 68;                  // xs staging stride
    __shared__ float hL[64 * PAD];
    int tid = threadIdx.x;
    int base = blockIdx.x * 64;

    // stage h tile coalesced
    {
        const float4* hg = reinterpret_cast<const float4*>(h + (size_t)base * DIN);
        const int T4 = 64 * DIN / 4;
        int lim = n - base;
        lim = (lim > 64) ? T4 : lim * (DIN / 4);
        for (int i = tid; i < T4; i += 256) {
            float4 v = (i < lim) ? hg[i] : make_float4(0.f, 0.f, 0.f, 0.f);
            int r = i / (DIN / 4), c = i % (DIN / 4);
            *reinterpret_cast<float4*>(&hL[r * PAD + c * 4]) = v;
        }
    }
    __syncthreads();

    int lane = tid & 63;
    int c0 = __builtin_amdgcn_readfirstlane((tid >> 6) << 4);   // wave-uniform col base
    float acc[16];
#pragma unroll
    for (int c = 0; c < 16; ++c) acc[c] = 0.f;
    float eacc = 0.f, dacc = 0.f;

    for (int k = 0; k < DIN; k += 4) {
        float4 hv = *reinterpret_cast<const float4*>(&hL[lane * PAD + k]);
        const float* w0 = Ws + (size_t)(k + 0) * DD + c0;
        const float* w1 = Ws + (size_t)(k + 1) * DD + c0;
        const float* w2 = Ws + (size_t)(k + 2) * DD + c0;
        const float* w3 = Ws + (size_t)(k + 3) * DD + c0;
#pragma unroll
        for (int c = 0; c < 16; ++c) {
            acc[c] = fmaf(hv.x, w0[c], acc[c]);
            acc[c] = fmaf(hv.y, w1[c], acc[c]);
            acc[c] = fmaf(hv.z, w2[c], acc[c]);
            acc[c] = fmaf(hv.w, w3[c], acc[c]);
        }
        eacc = fmaf(hv.x, wsas[k + 0], eacc); eacc = fmaf(hv.y, wsas[k + 1], eacc);
        eacc = fmaf(hv.z, wsas[k + 2], eacc); eacc = fmaf(hv.w, wsas[k + 3], eacc);
        dacc = fmaf(hv.x, wdad[k + 0], dacc); dacc = fmaf(hv.y, wdad[k + 1], dacc);
        dacc = fmaf(hv.z, wdad[k + 2], dacc); dacc = fmaf(hv.w, wdad[k + 3], dacc);
    }

    if ((tid >> 6) == 0 && base + lane < n) {   // identical across waves
        es[base + lane] = eacc;
        ed[base + lane] = dacc;
    }
    __syncthreads();                            // hL dead -> reuse as xs staging
    float* xsL = hL;
#pragma unroll
    for (int c = 0; c < 16; c += 4)
        *reinterpret_cast<float4*>(&xsL[lane * XP + c0 + c]) =
            make_float4(acc[c], acc[c + 1], acc[c + 2], acc[c + 3]);
    __syncthreads();
    {
        float4* xg = reinterpret_cast<float4*>(xs + (size_t)base * DD);
        for (int i = tid; i < 64 * 16; i += 256) {
            int r = i >> 4, c4 = i & 15;
            if (base + r < n)
                xg[i] = *reinterpret_cast<const float4*>(&xsL[r * XP + c4 * 4]);
        }
    }
}

// one wave per destination node, single pass (shift-invariant softmax, no max).
__global__ __launch_bounds__(256) void agg_k(
    const int* __restrict__ rowstart, const int* __restrict__ csr_src,
    const float* __restrict__ xs, const float* __restrict__ es,
    const float* __restrict__ ed, const float* __restrict__ bias,
    float* __restrict__ hout, int n) {
    int wid = (blockIdx.x * blockDim.x + threadIdx.x) >> 6;
    int lane = threadIdx.x & 63;
    if (wid >= n) return;
    int beg = rowstart[wid];
    int deg = rowstart[wid + 1] - beg;
    float edv = ed[wid];
    int slot = lane >> 4;
    int fl = lane & 15;

    float4 acc = make_float4(0.f, 0.f, 0.f, 0.f);
    float zl = 0.f;

    for (int c0 = 0; c0 < deg; c0 += 64) {
        int rem = min(64, deg - c0);
        int sv = 0;
        float pv = 0.f;
        if (lane < rem) {
            sv = csr_src[beg + c0 + lane];
            float e = es[sv] + edv;
            e = (e >= 0.f) ? e : NEG_SLOPE * e;
            pv = __expf(e);
        }
        zl += pv;
        int iters = (rem + 3) >> 2;
        for (int c = 0; c < iters; ++c) {
            int j = c * 4 + slot;
            float p = __shfl(pv, j, 64);
            int s = __shfl(sv, j, 64);
            float4 v = *reinterpret_cast<const float4*>(xs + (size_t)s * DD + fl * 4);
            acc.x = fmaf(p, v.x, acc.x);
            acc.y = fmaf(p, v.y, acc.y);
            acc.z = fmaf(p, v.z, acc.z);
            acc.w = fmaf(p, v.w, acc.w);
        }
    }

#pragma unroll
    for (int off = 32; off; off >>= 1) zl += __shfl_xor(zl, off, 64);
    acc.x += __shfl_xor(acc.x, 16, 64); acc.y += __shfl_xor(acc.y, 16, 64);
    acc.z += __shfl_xor(acc.z, 16, 64); acc.w += __shfl_xor(acc.w, 16, 64);
    acc.x += __shfl_xor(acc.x, 32, 64); acc.y += __shfl_xor(acc.y, 32, 64);
    acc.z += __shfl_xor(acc.z, 32, 64); acc.w += __shfl_xor(acc.w, 32, 64);

    float inv = 1.f / (zl + EPSV);
    float4 b4 = reinterpret_cast<const float4*>(bias)[fl];
    float4 val;
    val.x = fmaxf(fmaf(acc.x, inv, b4.x), 0.f);
    val.y = fmaxf(fmaf(acc.y, inv, b4.y), 0.f);
    val.z = fmaxf(fmaf(acc.z, inv, b4.z), 0.f);
    val.w = fmaxf(fmaf(acc.w, inv, b4.w), 0.f);
    if (slot == 0)
        *reinterpret_cast<float4*>(hout + (size_t)wid * DD + fl * 4) = val;
}

// layer-3 agg fused with mean-pool accumulation (no relu, no h write)
__global__ __launch_bounds__(256) void agg3_k(
    const int* __restrict__ rowstart, const int* __restrict__ csr_src,
    const float* __restrict__ xs, const float* __restrict__ es,
    const float* __restrict__ ed, const float* __restrict__ bias,
    const int* __restrict__ batch, float* __restrict__ psum, int n) {
    int wid = (blockIdx.x * blockDim.x + threadIdx.x) >> 6;
    int lane = threadIdx.x & 63;
    if (wid >= n) return;
    int beg = rowstart[wid];
    int deg = rowstart[wid + 1] - beg;
    float edv = ed[wid];
    int slot = lane >> 4;
    int fl = lane & 15;

    float4 acc = make_float4(0.f, 0.f, 0.f, 0.f);
    float zl = 0.f;

    for (int c0 = 0; c0 < deg; c0 += 64) {
        int rem = min(64, deg - c0);
        int sv = 0;
        float pv = 0.f;
        if (lane < rem) {
            sv = csr_src[beg + c0 + lane];
            float e = es[sv] + edv;
            e = (e >= 0.f) ? e : NEG_SLOPE * e;
            pv = __expf(e);
        }
        zl += pv;
        int iters = (rem + 3) >> 2;
        for (int c = 0; c < iters; ++c) {
            int j = c * 4 + slot;
            float p = __shfl(pv, j, 64);
            int s = __shfl(sv, j, 64);
            float4 v = *reinterpret_cast<const float4*>(xs + (size_t)s * DD + fl * 4);
            acc.x = fmaf(p, v.x, acc.x);
            acc.y = fmaf(p, v.y, acc.y);
            acc.z = fmaf(p, v.z, acc.z);
            acc.w = fmaf(p, v.w, acc.w);
        }
    }

#pragma unroll
    for (int off = 32; off; off >>= 1) zl += __shfl_xor(zl, off, 64);
    acc.x += __shfl_xor(acc.x, 16, 64); acc.y += __shfl_xor(acc.y, 16, 64);
    acc.z += __shfl_xor(acc.z, 16, 64); acc.w += __shfl_xor(acc.w, 16, 64);
    acc.x += __shfl_xor(acc.x, 32, 64); acc.y += __shfl_xor(acc.y, 32, 64);
    acc.z += __shfl_xor(acc.z, 32, 64); acc.w += __shfl_xor(acc.w, 32, 64);

    float inv = 1.f / (zl + EPSV);
    float4 b4 = reinterpret_cast<const float4*>(bias)[fl];
    if (slot == 0) {
        int g = batch[wid];
        float* p = psum + (size_t)g * DD + fl * 4;
        atomicAdd(p + 0, fmaf(acc.x, inv, b4.x));
        atomicAdd(p + 1, fmaf(acc.y, inv, b4.y));
        atomicAdd(p + 2, fmaf(acc.z, inv, b4.z));
        atomicAdd(p + 3, fmaf(acc.w, inv, b4.w));
    }
}

// final linear; per-graph counts from binary search on sorted batch
__global__ void final_k(const float* __restrict__ psum, const int* __restrict__ batch,
                        const float* __restrict__ post_emb,
                        const float* __restrict__ lin_w, const float* __restrict__ lin_b,
                        float* __restrict__ out) {
    __shared__ int sL[GG + 1];
    int r = threadIdx.x;
    if (r <= GG) {                        // lower_bound(batch, r)
        int lo = 0, hi = NN;
        while (lo < hi) {
            int m = (lo + hi) >> 1;
            if (batch[m] < r) lo = m + 1; else hi = m;
        }
        sL[r] = lo;
    }
    __syncthreads();
    if (r >= 2 * GG) return;
    float o0 = 0.f, o1 = 0.f;
    if (r < GG) {
        float c = fmaxf((float)(sL[r + 1] - sL[r]), 1.f);
        float inv = 1.f / c;
        for (int d2 = 0; d2 < DD; ++d2) {
            float v = psum[r * DD + d2] * inv;
            o0 = fmaf(v, lin_w[d2 * 2 + 0], o0);
            o1 = fmaf(v, lin_w[d2 * 2 + 1], o1);
        }
    } else {
        const float* pe = post_emb + (size_t)(r - GG) * DD;
        for (int d2 = 0; d2 < DD; ++d2) {
            float v = pe[d2];
            o0 = fmaf(v, lin_w[d2 * 2 + 0], o0);
            o1 = fmaf(v, lin_w[d2 * 2 + 1], o1);
        }
    }
    out[r * 2 + 0] = o0 + lin_b[0];
    out[r * 2 + 1] = o1 + lin_b[1];
}

// ---------------- host ----------------

extern "C" void kernel_launch(void* const* d_in, const int* in_sizes, int n_in,
                              void* d_out, int out_size, void* d_ws, size_t ws_size,
                              hipStream_t stream) {
    const float* x        = (const float*)d_in[0];
    const int*   ei       = (const int*)d_in[1];
    const int*   src      = ei;
    const int*   dst      = ei + EE;
    const int*   batch    = (const int*)d_in[2];
    const float* post_emb = (const float*)d_in[3];
    const float* Ws[3] = {(const float*)d_in[4],  (const float*)d_in[9],  (const float*)d_in[14]};
    const float* Wd[3] = {(const float*)d_in[5],  (const float*)d_in[10], (const float*)d_in[15]};
    const float* av[3] = {(const float*)d_in[6],  (const float*)d_in[11], (const float*)d_in[16]};
    const float* ad[3] = {(const float*)d_in[7],  (const float*)d_in[12], (const float*)d_in[17]};
    const float* bb[3] = {(const float*)d_in[8],  (const float*)d_in[13], (const float*)d_in[18]};
    const float* lin_w = (const float*)d_in[19];
    const float* lin_b = (const float*)d_in[20];
    float* outp = (float*)d_out;

    char* w = (char*)d_ws;
    size_t off = 0;
    auto alloc = [&](size_t bytes) -> char* {
        char* p = w + off;
        off += (bytes + 255) & ~(size_t)255;
        return p;
    };
    float*        xs       = (float*)alloc((size_t)NN * DD * 4);
    float*        h        = (float*)alloc((size_t)NN * DD * 4);
    float*        es       = (float*)alloc((size_t)NN * 4);
    float*        ed       = (float*)alloc((size_t)NN * 4);
    int*          rowstart = (int*)alloc((size_t)(NN + 1) * 4);
    int*          counts   = (int*)alloc((size_t)NN * 4);
    int*          csr      = (int*)alloc((size_t)EE * 4);
    int*          bsum     = (int*)alloc(1024);
    float*        wdadAll  = (float*)alloc(3 * FF * 4);
    float*        wsasAll  = (float*)alloc(3 * FF * 4);
    float*        psum     = (float*)alloc((size_t)GG * DD * 4);
    unsigned int* gbuf     = (unsigned int*)alloc((size_t)NBKT * BCAP * 4);
    int*          gcur     = (int*)alloc(256 * 4);

    // ---- CSR build: bin -> bucket-hist -> scan -> place ----
    hipMemsetAsync(gcur, 0, 256 * 4, stream);
    hipMemsetAsync(psum, 0, (size_t)GG * DD * 4, stream);
    bin_k<<<NCH, 256, 0, stream>>>(src, dst, gbuf, gcur);
    bhist_k<<<NBKT, 256, 0, stream>>>(gbuf, gcur, counts);
    int nb = (NN + SCAN_B - 1) / SCAN_B;   // 196
    scan1_k<<<nb, SCAN_B, 0, stream>>>(counts, rowstart, bsum, NN);
    scan2_k<<<1, SCAN_B, 0, stream>>>(bsum, nb);
    scan3_k<<<nb, SCAN_B, 0, stream>>>(rowstart, bsum, NN);
    place_k<<<NBKT, 256, 0, stream>>>(gbuf, gcur, rowstart, csr);

    // ---- per-layer projection vectors ----
    vecs3_k<<<3, 128, 0, stream>>>(Wd[0], ad[0], Ws[0], av[0],
                                   Wd[1], ad[1], Ws[1], av[1],
                                   Wd[2], ad[2], Ws[2], av[2], wdadAll, wsasAll);

    // ---- 3 GAT layers ----
    const int XB = (NN + 63) / 64;        // 782 blocks: 64 rows per block
    const float* hin = x;
    for (int l = 0; l < 3; ++l) {
        if (l == 0)
            xform_k<FF><<<XB, 256, 0, stream>>>(hin, Ws[l], wsasAll + l * FF,
                                                wdadAll + l * FF, xs, es, ed, NN);
        else
            xform_k<DD><<<XB, 256, 0, stream>>>(hin, Ws[l], wsasAll + l * FF,
                                                wdadAll + l * FF, xs, es, ed, NN);
        if (l < 2)
            agg_k<<<(NN * 64 + 255) / 256, 256, 0, stream>>>(rowstart, csr, xs, es, ed,
                                                             bb[l], h, NN);
        else
            agg3_k<<<(NN * 64 + 255) / 256, 256, 0, stream>>>(rowstart, csr, xs, es, ed,
                                                              bb[l], batch, psum, NN);
        hin = h;
    }

    // ---- final linear (counts via binary search on sorted batch) ----
    final_k<<<1, 128, 0, stream>>>(psum, batch, post_emb, lin_w, lin_b, outp);
}

// Round 8
// 212.771 us; speedup vs baseline: 2.0984x; 2.0984x over previous
//
#include <hip/hip_runtime.h>
#include <math.h>

#define NN 50000
#define FF 128
#define DD 64
#define EE 800000
#define GG 64
#define NEG_SLOPE 0.2f
#define EPSV 1e-16f

// CSR-build bucketing: coarse bucket = dst>>8 (256 nodes each)
#define NBKT 196                     // ceil(NN/256)
#define BCAP 5120                    // max edges/bucket (mean 4096)
#define CHUNK 2048
#define NCH ((EE + CHUNK - 1) / CHUNK)   // 391

// ---------------- CSR build (LDS counting sort) ----------------

__global__ __launch_bounds__(256) void bin_k(const int* __restrict__ src,
                                             const int* __restrict__ dst,
                                             unsigned int* __restrict__ gbuf,
                                             int* __restrict__ gcur) {
    __shared__ unsigned int staged[CHUNK];
    __shared__ int bcnt[256], bstart[256], runbase[256];
    int tid = threadIdx.x;
    bcnt[tid] = 0;
    __syncthreads();
    int base = blockIdx.x * CHUNK;
    int cnt = min(CHUNK, EE - base);
    unsigned int pe[8];
    int bk[8], lofs[8];
#pragma unroll
    for (int k = 0; k < 8; ++k) {
        int i = tid + k * 256;
        bk[k] = -1;
        if (i < cnt) {
            unsigned int s = (unsigned int)src[base + i];
            unsigned int d = (unsigned int)dst[base + i];
            pe[k] = (s << 16) | d;
            bk[k] = (int)(d >> 8);
            lofs[k] = atomicAdd(&bcnt[bk[k]], 1);
        }
    }
    __syncthreads();
    int v = bcnt[tid];
    bstart[tid] = v;
    __syncthreads();
    for (int off = 1; off < 256; off <<= 1) {
        int t = (tid >= off) ? bstart[tid - off] : 0;
        __syncthreads();
        bstart[tid] += t;
        __syncthreads();
    }
    int excl = bstart[tid] - v;
    __syncthreads();
    bstart[tid] = excl;
    __syncthreads();
#pragma unroll
    for (int k = 0; k < 8; ++k)
        if (bk[k] >= 0) staged[bstart[bk[k]] + lofs[k]] = pe[k];
    runbase[tid] = atomicAdd(&gcur[tid], bcnt[tid]);
    __syncthreads();
    for (int i = tid; i < cnt; i += 256) {
        unsigned int p = staged[i];
        int b = (int)((p & 0xFFFFu) >> 8);
        gbuf[(size_t)b * BCAP + runbase[b] + (i - bstart[b])] = p;
    }
}

__global__ __launch_bounds__(256) void bhist_k(const unsigned int* __restrict__ gbuf,
                                               const int* __restrict__ gcur,
                                               int* __restrict__ counts) {
    __shared__ int c2[256];
    int tid = threadIdx.x, b = blockIdx.x;
    c2[tid] = 0;
    __syncthreads();
    int nb = gcur[b];
    const unsigned int* bb = gbuf + (size_t)b * BCAP;
    for (int i = tid; i < nb; i += 256)
        atomicAdd(&c2[bb[i] & 255u], 1);
    __syncthreads();
    int node = b * 256 + tid;
    if (node < NN) counts[node] = c2[tid];
}

#define SCAN_B 256

__global__ void scan1_k(const int* __restrict__ in, int* __restrict__ out,
                        int* __restrict__ bsum, int n) {
    __shared__ int s[SCAN_B];
    int gid = blockIdx.x * SCAN_B + threadIdx.x;
    int v = (gid < n) ? in[gid] : 0;
    s[threadIdx.x] = v;
    __syncthreads();
    for (int off = 1; off < SCAN_B; off <<= 1) {
        int t = (threadIdx.x >= off) ? s[threadIdx.x - off] : 0;
        __syncthreads();
        s[threadIdx.x] += t;
        __syncthreads();
    }
    if (gid < n) out[gid] = s[threadIdx.x] - v;
    if (threadIdx.x == SCAN_B - 1) bsum[blockIdx.x] = s[threadIdx.x];
}

__global__ void scan2_k(int* bsum, int nb) {
    __shared__ int s[SCAN_B];
    int v = (threadIdx.x < nb) ? bsum[threadIdx.x] : 0;
    s[threadIdx.x] = v;
    __syncthreads();
    for (int off = 1; off < 256; off <<= 1) {
        int t = (threadIdx.x >= off) ? s[threadIdx.x - off] : 0;
        __syncthreads();
        s[threadIdx.x] += t;
        __syncthreads();
    }
    if (threadIdx.x < nb) bsum[threadIdx.x] = s[threadIdx.x] - v;
}

__global__ void scan3_k(int* __restrict__ rowstart, const int* __restrict__ bsum, int n) {
    int gid = blockIdx.x * SCAN_B + threadIdx.x;
    if (gid < n) rowstart[gid] += bsum[blockIdx.x];
    if (gid == 0) rowstart[n] = EE;
}

__global__ __launch_bounds__(256) void place_k(const unsigned int* __restrict__ gbuf,
                                               const int* __restrict__ gcur,
                                               const int* __restrict__ rowstart,
                                               int* __restrict__ csr) {
    __shared__ int rs[256];
    __shared__ int cur[256];
    int tid = threadIdx.x, b = blockIdx.x;
    int node = b * 256 + tid;
    rs[tid] = (node < NN) ? rowstart[node] : 0;
    cur[tid] = 0;
    __syncthreads();
    int nb = gcur[b];
    const unsigned int* bb = gbuf + (size_t)b * BCAP;
    for (int i = tid; i < nb; i += 256) {
        unsigned int p = bb[i];
        int l = (int)(p & 255u);
        int pos = rs[l] + atomicAdd(&cur[l], 1);
        csr[pos] = (int)(p >> 16);
    }
}

// ---------------- per-layer kernels ----------------

// per layer: wdad[k] = Wd[k,:].ad ; wsas[k] = Ws[k,:].as
__global__ void vecs3_k(const float* __restrict__ Wd0, const float* __restrict__ ad0,
                        const float* __restrict__ Ws0, const float* __restrict__ as0,
                        const float* __restrict__ Wd1, const float* __restrict__ ad1,
                        const float* __restrict__ Ws1, const float* __restrict__ as1,
                        const float* __restrict__ Wd2, const float* __restrict__ ad2,
                        const float* __restrict__ Ws2, const float* __restrict__ as2,
                        float* __restrict__ wdadAll, float* __restrict__ wsasAll) {
    int b = blockIdx.x;
    const float* Wd = (b == 0) ? Wd0 : (b == 1) ? Wd1 : Wd2;
    const float* ad = (b == 0) ? ad0 : (b == 1) ? ad1 : ad2;
    const float* Ws = (b == 0) ? Ws0 : (b == 1) ? Ws1 : Ws2;
    const float* as = (b == 0) ? as0 : (b == 1) ? as1 : as2;
    int Din = (b == 0) ? FF : DD;
    int k = threadIdx.x;
    if (k < Din) {
        float accd = 0.f, accs = 0.f;
        for (int d2 = 0; d2 < DD; ++d2) {
            accd += Wd[k * DD + d2] * ad[d2];
            accs += Ws[k * DD + d2] * as[d2];
        }
        wdadAll[b * FF + k] = accd;
        wsasAll[b * FF + k] = accs;
    }
}

// xs = h @ Ws ; es = h @ (Ws@a_s) ; ed = h @ (Wd@a_d)
// lane = row (64 rows/block), wave = 16-col slice. h per-lane from padded LDS
// (1 ds_read_b128 per 4k); Ws/wsas/wdad wave-uniform -> scalar pipe.
template <int DIN>
__global__ __launch_bounds__(256, 4) void xform_k(
    const float* __restrict__ h, const float* __restrict__ Ws,
    const float* __restrict__ wsas, const float* __restrict__ wdad,
    float* __restrict__ xs, float* __restrict__ es, float* __restrict__ ed,
    int n) {
    constexpr int PAD = DIN + 4;            // 132 / 68: b128-aligned, max-rate banks
    constexpr int XP = 68;                  // xs staging stride
    __shared__ float hL[64 * PAD];
    int tid = threadIdx.x;
    int base = blockIdx.x * 64;

    // stage h tile coalesced
    {
        const float4* hg = reinterpret_cast<const float4*>(h + (size_t)base * DIN);
        const int T4 = 64 * DIN / 4;
        int lim = n - base;
        lim = (lim > 64) ? T4 : lim * (DIN / 4);
        for (int i = tid; i < T4; i += 256) {
            float4 v = (i < lim) ? hg[i] : make_float4(0.f, 0.f, 0.f, 0.f);
            int r = i / (DIN / 4), c = i % (DIN / 4);
            *reinterpret_cast<float4*>(&hL[r * PAD + c * 4]) = v;
        }
    }
    __syncthreads();

    int lane = tid & 63;
    int c0 = __builtin_amdgcn_readfirstlane((tid >> 6) << 4);   // wave-uniform col base
    float acc[16];
#pragma unroll
    for (int c = 0; c < 16; ++c) acc[c] = 0.f;
    float eacc = 0.f, dacc = 0.f;

    for (int k = 0; k < DIN; k += 4) {
        float4 hv = *reinterpret_cast<const float4*>(&hL[lane * PAD + k]);
        const float* w0 = Ws + (size_t)(k + 0) * DD + c0;
        const float* w1 = Ws + (size_t)(k + 1) * DD + c0;
        const float* w2 = Ws + (size_t)(k + 2) * DD + c0;
        const float* w3 = Ws + (size_t)(k + 3) * DD + c0;
#pragma unroll
        for (int c = 0; c < 16; ++c) {
            acc[c] = fmaf(hv.x, w0[c], acc[c]);
            acc[c] = fmaf(hv.y, w1[c], acc[c]);
            acc[c] = fmaf(hv.z, w2[c], acc[c]);
            acc[c] = fmaf(hv.w, w3[c], acc[c]);
        }
        eacc = fmaf(hv.x, wsas[k + 0], eacc); eacc = fmaf(hv.y, wsas[k + 1], eacc);
        eacc = fmaf(hv.z, wsas[k + 2], eacc); eacc = fmaf(hv.w, wsas[k + 3], eacc);
        dacc = fmaf(hv.x, wdad[k + 0], dacc); dacc = fmaf(hv.y, wdad[k + 1], dacc);
        dacc = fmaf(hv.z, wdad[k + 2], dacc); dacc = fmaf(hv.w, wdad[k + 3], dacc);
    }

    if ((tid >> 6) == 0 && base + lane < n) {   // identical across waves
        es[base + lane] = eacc;
        ed[base + lane] = dacc;
    }
    __syncthreads();                            // hL dead -> reuse as xs staging
    float* xsL = hL;
#pragma unroll
    for (int c = 0; c < 16; c += 4)
        *reinterpret_cast<float4*>(&xsL[lane * XP + c0 + c]) =
            make_float4(acc[c], acc[c + 1], acc[c + 2], acc[c + 3]);
    __syncthreads();
    {
        float4* xg = reinterpret_cast<float4*>(xs + (size_t)base * DD);
        for (int i = tid; i < 64 * 16; i += 256) {
            int r = i >> 4, c4 = i & 15;
            if (base + r < n)
                xg[i] = *reinterpret_cast<const float4*>(&xsL[r * XP + c4 * 4]);
        }
    }
}

// one wave per destination node, single pass (shift-invariant softmax, no max).
__global__ __launch_bounds__(256) void agg_k(
    const int* __restrict__ rowstart, const int* __restrict__ csr_src,
    const float* __restrict__ xs, const float* __restrict__ es,
    const float* __restrict__ ed, const float* __restrict__ bias,
    float* __restrict__ hout, int n, int relu) {
    int wid = (blockIdx.x * blockDim.x + threadIdx.x) >> 6;
    int lane = threadIdx.x & 63;
    if (wid >= n) return;
    int beg = rowstart[wid];
    int deg = rowstart[wid + 1] - beg;
    float edv = ed[wid];
    int slot = lane >> 4;
    int fl = lane & 15;

    float4 acc = make_float4(0.f, 0.f, 0.f, 0.f);
    float zl = 0.f;

    for (int c0 = 0; c0 < deg; c0 += 64) {
        int rem = min(64, deg - c0);
        int sv = 0;
        float pv = 0.f;
        if (lane < rem) {
            sv = csr_src[beg + c0 + lane];
            float e = es[sv] + edv;
            e = (e >= 0.f) ? e : NEG_SLOPE * e;
            pv = __expf(e);
        }
        zl += pv;
        int iters = (rem + 3) >> 2;
        for (int c = 0; c < iters; ++c) {
            int j = c * 4 + slot;
            float p = __shfl(pv, j, 64);
            int s = __shfl(sv, j, 64);
            float4 v = *reinterpret_cast<const float4*>(xs + (size_t)s * DD + fl * 4);
            acc.x = fmaf(p, v.x, acc.x);
            acc.y = fmaf(p, v.y, acc.y);
            acc.z = fmaf(p, v.z, acc.z);
            acc.w = fmaf(p, v.w, acc.w);
        }
    }

#pragma unroll
    for (int off = 32; off; off >>= 1) zl += __shfl_xor(zl, off, 64);
    acc.x += __shfl_xor(acc.x, 16, 64); acc.y += __shfl_xor(acc.y, 16, 64);
    acc.z += __shfl_xor(acc.z, 16, 64); acc.w += __shfl_xor(acc.w, 16, 64);
    acc.x += __shfl_xor(acc.x, 32, 64); acc.y += __shfl_xor(acc.y, 32, 64);
    acc.z += __shfl_xor(acc.z, 32, 64); acc.w += __shfl_xor(acc.w, 32, 64);

    float inv = 1.f / (zl + EPSV);
    float4 b4 = reinterpret_cast<const float4*>(bias)[fl];
    float4 val;
    val.x = fmaf(acc.x, inv, b4.x);
    val.y = fmaf(acc.y, inv, b4.y);
    val.z = fmaf(acc.z, inv, b4.z);
    val.w = fmaf(acc.w, inv, b4.w);
    if (relu) {
        val.x = fmaxf(val.x, 0.f); val.y = fmaxf(val.y, 0.f);
        val.z = fmaxf(val.z, 0.f); val.w = fmaxf(val.w, 0.f);
    }
    if (slot == 0)
        *reinterpret_cast<float4*>(hout + (size_t)wid * DD + fl * 4) = val;
}

// ---------------- pooling + final linear ----------------

// one wave handles 16 consecutive (batch-sorted) nodes; run-length flush
// (~220K atomics total, ~55/address — low contention, measured fine in r5/6)
__global__ __launch_bounds__(256) void pool_k(
    const float* __restrict__ h, const int* __restrict__ batch,
    float* __restrict__ psum, int n) {
    int wid = (blockIdx.x * blockDim.x + threadIdx.x) >> 6;
    int lane = threadIdx.x & 63;
    int beg = wid * 16;
    if (beg >= n) return;
    int end = min(beg + 16, n);
    int curg = batch[beg];
    float acc = 0.f;
    for (int i = beg; i < end; ++i) {
        int g = batch[i];
        if (g != curg) {
            atomicAdd(&psum[curg * DD + lane], acc);
            acc = 0.f; curg = g;
        }
        acc += h[(size_t)i * DD + lane];
    }
    atomicAdd(&psum[curg * DD + lane], acc);
}

// final linear; per-graph counts from binary search on sorted batch
__global__ void final_k(const float* __restrict__ psum, const int* __restrict__ batch,
                        const float* __restrict__ post_emb,
                        const float* __restrict__ lin_w, const float* __restrict__ lin_b,
                        float* __restrict__ out) {
    __shared__ int sL[GG + 1];
    int r = threadIdx.x;
    if (r <= GG) {                        // lower_bound(batch, r)
        int lo = 0, hi = NN;
        while (lo < hi) {
            int m = (lo + hi) >> 1;
            if (batch[m] < r) lo = m + 1; else hi = m;
        }
        sL[r] = lo;
    }
    __syncthreads();
    if (r >= 2 * GG) return;
    float o0 = 0.f, o1 = 0.f;
    if (r < GG) {
        float c = fmaxf((float)(sL[r + 1] - sL[r]), 1.f);
        float inv = 1.f / c;
        for (int d2 = 0; d2 < DD; ++d2) {
            float v = psum[r * DD + d2] * inv;
            o0 = fmaf(v, lin_w[d2 * 2 + 0], o0);
            o1 = fmaf(v, lin_w[d2 * 2 + 1], o1);
        }
    } else {
        const float* pe = post_emb + (size_t)(r - GG) * DD;
        for (int d2 = 0; d2 < DD; ++d2) {
            float v = pe[d2];
            o0 = fmaf(v, lin_w[d2 * 2 + 0], o0);
            o1 = fmaf(v, lin_w[d2 * 2 + 1], o1);
        }
    }
    out[r * 2 + 0] = o0 + lin_b[0];
    out[r * 2 + 1] = o1 + lin_b[1];
}

// ---------------- host ----------------

extern "C" void kernel_launch(void* const* d_in, const int* in_sizes, int n_in,
                              void* d_out, int out_size, void* d_ws, size_t ws_size,
                              hipStream_t stream) {
    const float* x        = (const float*)d_in[0];
    const int*   ei       = (const int*)d_in[1];
    const int*   src      = ei;
    const int*   dst      = ei + EE;
    const int*   batch    = (const int*)d_in[2];
    const float* post_emb = (const float*)d_in[3];
    const float* Ws[3] = {(const float*)d_in[4],  (const float*)d_in[9],  (const float*)d_in[14]};
    const float* Wd[3] = {(const float*)d_in[5],  (const float*)d_in[10], (const float*)d_in[15]};
    const float* av[3] = {(const float*)d_in[6],  (const float*)d_in[11], (const float*)d_in[16]};
    const float* ad[3] = {(const float*)d_in[7],  (const float*)d_in[12], (const float*)d_in[17]};
    const float* bb[3] = {(const float*)d_in[8],  (const float*)d_in[13], (const float*)d_in[18]};
    const float* lin_w = (const float*)d_in[19];
    const float* lin_b = (const float*)d_in[20];
    float* outp = (float*)d_out;

    char* w = (char*)d_ws;
    size_t off = 0;
    auto alloc = [&](size_t bytes) -> char* {
        char* p = w + off;
        off += (bytes + 255) & ~(size_t)255;
        return p;
    };
    float*        xs       = (float*)alloc((size_t)NN * DD * 4);
    float*        h        = (float*)alloc((size_t)NN * DD * 4);
    float*        es       = (float*)alloc((size_t)NN * 4);
    float*        ed       = (float*)alloc((size_t)NN * 4);
    int*          rowstart = (int*)alloc((size_t)(NN + 1) * 4);
    int*          counts   = (int*)alloc((size_t)NN * 4);
    int*          csr      = (int*)alloc((size_t)EE * 4);
    int*          bsum     = (int*)alloc(1024);
    float*        wdadAll  = (float*)alloc(3 * FF * 4);
    float*        wsasAll  = (float*)alloc(3 * FF * 4);
    float*        psum     = (float*)alloc((size_t)GG * DD * 4);
    unsigned int* gbuf     = (unsigned int*)alloc((size_t)NBKT * BCAP * 4);
    int*          gcur     = (int*)alloc(256 * 4);

    // ---- CSR build: bin -> bucket-hist -> scan -> place ----
    hipMemsetAsync(gcur, 0, 256 * 4, stream);
    hipMemsetAsync(psum, 0, (size_t)GG * DD * 4, stream);
    bin_k<<<NCH, 256, 0, stream>>>(src, dst, gbuf, gcur);
    bhist_k<<<NBKT, 256, 0, stream>>>(gbuf, gcur, counts);
    int nb = (NN + SCAN_B - 1) / SCAN_B;   // 196
    scan1_k<<<nb, SCAN_B, 0, stream>>>(counts, rowstart, bsum, NN);
    scan2_k<<<1, SCAN_B, 0, stream>>>(bsum, nb);
    scan3_k<<<nb, SCAN_B, 0, stream>>>(rowstart, bsum, NN);
    place_k<<<NBKT, 256, 0, stream>>>(gbuf, gcur, rowstart, csr);

    // ---- per-layer projection vectors ----
    vecs3_k<<<3, 128, 0, stream>>>(Wd[0], ad[0], Ws[0], av[0],
                                   Wd[1], ad[1], Ws[1], av[1],
                                   Wd[2], ad[2], Ws[2], av[2], wdadAll, wsasAll);

    // ---- 3 GAT layers ----
    const int XB = (NN + 63) / 64;        // 782 blocks: 64 rows per block
    const float* hin = x;
    for (int l = 0; l < 3; ++l) {
        if (l == 0)
            xform_k<FF><<<XB, 256, 0, stream>>>(hin, Ws[l], wsasAll + l * FF,
                                                wdadAll + l * FF, xs, es, ed, NN);
        else
            xform_k<DD><<<XB, 256, 0, stream>>>(hin, Ws[l], wsasAll + l * FF,
                                                wdadAll + l * FF, xs, es, ed, NN);
        agg_k<<<(NN * 64 + 255) / 256, 256, 0, stream>>>(rowstart, csr, xs, es, ed,
                                                         bb[l], h, NN, (l < 2) ? 1 : 0);
        hin = h;
    }

    // ---- pooling + final linear ----
    pool_k<<<((NN + 15) / 16 * 64 + 255) / 256, 256, 0, stream>>>(h, batch, psum, NN);
    final_k<<<1, 128, 0, stream>>>(psum, batch, post_emb, lin_w, lin_b, outp);
}

// Round 9
// 189.619 us; speedup vs baseline: 2.3547x; 1.1221x over previous
//
#include <hip/hip_runtime.h>
#include <hip/hip_fp16.h>
#include <math.h>

#define NN 50000
#define FF 128
#define DD 64
#define EE 800000
#define GG 64
#define NEG_SLOPE 0.2f
#define EPSV 1e-16f

// CSR-build bucketing: coarse bucket = dst>>8 (256 nodes each)
#define NBKT 196                     // ceil(NN/256)
#define BCAP 5120                    // max edges/bucket (mean 4096, +16 sigma)
#define CHUNK 4096
#define NCH ((EE + CHUNK - 1) / CHUNK)   // 196

// ---------------- CSR build ----------------

// Pass 1: bin edges into per-bucket global regions with LDS staging.
// Packed edge = (src<<16)|dst (both < 65536).
__global__ __launch_bounds__(256) void bin_k(const int* __restrict__ src,
                                             const int* __restrict__ dst,
                                             unsigned int* __restrict__ gbuf,
                                             int* __restrict__ gcur) {
    __shared__ unsigned int staged[CHUNK];     // 16 KB
    __shared__ int bc[256], bs[256], rb[256];
    int tid = threadIdx.x;
    bc[tid] = 0;
    __syncthreads();
    int base = blockIdx.x * CHUNK;
    int cnt = min(CHUNK, EE - base);
    // count
    for (int i = tid; i < cnt; i += 256)
        atomicAdd(&bc[((unsigned)dst[base + i]) >> 8], 1);
    __syncthreads();
    int v = bc[tid];
    bs[tid] = v;
    __syncthreads();
    for (int off = 1; off < 256; off <<= 1) {
        int t = (tid >= off) ? bs[tid - off] : 0;
        __syncthreads();
        bs[tid] += t;
        __syncthreads();
    }
    int excl = bs[tid] - v;
    __syncthreads();
    bs[tid] = excl;                 // bucket start within chunk
    bc[tid] = excl;                 // cursor
    rb[tid] = atomicAdd(&gcur[tid], v);   // global run base for this bucket
    __syncthreads();
    // place into LDS sorted-by-bucket
    for (int i = tid; i < cnt; i += 256) {
        unsigned int d = (unsigned)dst[base + i];
        unsigned int s = (unsigned)src[base + i];
        int pos = atomicAdd(&bc[d >> 8], 1);
        staged[pos] = (s << 16) | d;
    }
    __syncthreads();
    // flush contiguous runs per bucket
    for (int i = tid; i < cnt; i += 256) {
        unsigned int p = staged[i];
        int b = (int)((p & 0xFFFFu) >> 8);
        gbuf[(size_t)b * BCAP + rb[b] + (i - bs[b])] = p;
    }
}

// tiny: exclusive prefix over bucket totals; rowstart[NN]=EE
__global__ void bpre_k(const int* __restrict__ gcur, int* __restrict__ bktoff,
                       int* __restrict__ rowstart) {
    __shared__ int s[256];
    int tid = threadIdx.x;
    int v = (tid < NBKT) ? gcur[tid] : 0;
    s[tid] = v;
    __syncthreads();
    for (int off = 1; off < 256; off <<= 1) {
        int t = (tid >= off) ? s[tid - off] : 0;
        __syncthreads();
        s[tid] += t;
        __syncthreads();
    }
    bktoff[tid] = s[tid] - v;
    if (tid == 0) rowstart[NN] = EE;
}

// Pass 2 (merged hist+scan+rowstart+place): one block per bucket, edges staged
// once in LDS; csr writes land in the bucket's contiguous region.
__global__ __launch_bounds__(256) void build_k(const unsigned int* __restrict__ gbuf,
                                               const int* __restrict__ gcur,
                                               const int* __restrict__ bktoff,
                                               int* __restrict__ rowstart,
                                               int* __restrict__ csr) {
    __shared__ unsigned int st[BCAP];          // 20 KB
    __shared__ int hist[256], sc[256], cur[256];
    int tid = threadIdx.x, b = blockIdx.x;
    hist[tid] = 0;
    __syncthreads();
    int nb = gcur[b];
    const unsigned int* bb = gbuf + (size_t)b * BCAP;
    for (int i = tid; i < nb; i += 256) {
        unsigned int p = bb[i];
        st[i] = p;
        atomicAdd(&hist[p & 255u], 1);
    }
    __syncthreads();
    int v = hist[tid];
    sc[tid] = v;
    __syncthreads();
    for (int off = 1; off < 256; off <<= 1) {
        int t = (tid >= off) ? sc[tid - off] : 0;
        __syncthreads();
        sc[tid] += t;
        __syncthreads();
    }
    int rs = bktoff[b] + sc[tid] - v;          // exclusive
    int node = b * 256 + tid;
    if (node < NN) rowstart[node] = rs;
    cur[tid] = rs;
    __syncthreads();
    for (int i = tid; i < nb; i += 256) {
        unsigned int p = st[i];
        int pos = atomicAdd(&cur[p & 255u], 1);
        csr[pos] = (int)(p >> 16);
    }
}

// ---------------- per-layer kernels ----------------

// per layer: wdad[k] = Wd[k,:].ad ; wsas[k] = Ws[k,:].as
__global__ void vecs3_k(const float* __restrict__ Wd0, const float* __restrict__ ad0,
                        const float* __restrict__ Ws0, const float* __restrict__ as0,
                        const float* __restrict__ Wd1, const float* __restrict__ ad1,
                        const float* __restrict__ Ws1, const float* __restrict__ as1,
                        const float* __restrict__ Wd2, const float* __restrict__ ad2,
                        const float* __restrict__ Ws2, const float* __restrict__ as2,
                        float* __restrict__ wdadAll, float* __restrict__ wsasAll) {
    int b = blockIdx.x;
    const float* Wd = (b == 0) ? Wd0 : (b == 1) ? Wd1 : Wd2;
    const float* ad = (b == 0) ? ad0 : (b == 1) ? ad1 : ad2;
    const float* Ws = (b == 0) ? Ws0 : (b == 1) ? Ws1 : Ws2;
    const float* as = (b == 0) ? as0 : (b == 1) ? as1 : as2;
    int Din = (b == 0) ? FF : DD;
    int k = threadIdx.x;
    if (k < Din) {
        float accd = 0.f, accs = 0.f;
        for (int d2 = 0; d2 < DD; ++d2) {
            accd += Wd[k * DD + d2] * ad[d2];
            accs += Ws[k * DD + d2] * as[d2];
        }
        wdadAll[b * FF + k] = accd;
        wsasAll[b * FF + k] = accs;
    }
}

// xs(fp16) = h @ Ws ; es = h @ (Ws@a_s) ; ed = h @ (Wd@a_d)
// lane = row (64 rows/block), wave = 16-col slice. h per-lane from padded LDS;
// Ws wave-uniform -> scalar pipe. xs written as __half via LDS transpose.
template <int DIN>
__global__ __launch_bounds__(256, 4) void xform_k(
    const float* __restrict__ h, const float* __restrict__ Ws,
    const float* __restrict__ wsas, const float* __restrict__ wdad,
    __half* __restrict__ xs, float* __restrict__ es, float* __restrict__ ed,
    int n) {
    constexpr int PAD = DIN + 4;
    constexpr int XP = 68;
    __shared__ float hL[64 * PAD];
    int tid = threadIdx.x;
    int base = blockIdx.x * 64;

    {
        const float4* hg = reinterpret_cast<const float4*>(h + (size_t)base * DIN);
        const int T4 = 64 * DIN / 4;
        int lim = n - base;
        lim = (lim > 64) ? T4 : lim * (DIN / 4);
        for (int i = tid; i < T4; i += 256) {
            float4 v = (i < lim) ? hg[i] : make_float4(0.f, 0.f, 0.f, 0.f);
            int r = i / (DIN / 4), c = i % (DIN / 4);
            *reinterpret_cast<float4*>(&hL[r * PAD + c * 4]) = v;
        }
    }
    __syncthreads();

    int lane = tid & 63;
    int c0 = __builtin_amdgcn_readfirstlane((tid >> 6) << 4);
    float acc[16];
#pragma unroll
    for (int c = 0; c < 16; ++c) acc[c] = 0.f;
    float eacc = 0.f, dacc = 0.f;

    for (int k = 0; k < DIN; k += 4) {
        float4 hv = *reinterpret_cast<const float4*>(&hL[lane * PAD + k]);
        const float* w0 = Ws + (size_t)(k + 0) * DD + c0;
        const float* w1 = Ws + (size_t)(k + 1) * DD + c0;
        const float* w2 = Ws + (size_t)(k + 2) * DD + c0;
        const float* w3 = Ws + (size_t)(k + 3) * DD + c0;
#pragma unroll
        for (int c = 0; c < 16; ++c) {
            acc[c] = fmaf(hv.x, w0[c], acc[c]);
            acc[c] = fmaf(hv.y, w1[c], acc[c]);
            acc[c] = fmaf(hv.z, w2[c], acc[c]);
            acc[c] = fmaf(hv.w, w3[c], acc[c]);
        }
        eacc = fmaf(hv.x, wsas[k + 0], eacc); eacc = fmaf(hv.y, wsas[k + 1], eacc);
        eacc = fmaf(hv.z, wsas[k + 2], eacc); eacc = fmaf(hv.w, wsas[k + 3], eacc);
        dacc = fmaf(hv.x, wdad[k + 0], dacc); dacc = fmaf(hv.y, wdad[k + 1], dacc);
        dacc = fmaf(hv.z, wdad[k + 2], dacc); dacc = fmaf(hv.w, wdad[k + 3], dacc);
    }

    if ((tid >> 6) == 0 && base + lane < n) {
        es[base + lane] = eacc;
        ed[base + lane] = dacc;
    }
    __syncthreads();                            // hL dead -> reuse as xs staging
    float* xsL = hL;
#pragma unroll
    for (int c = 0; c < 16; c += 4)
        *reinterpret_cast<float4*>(&xsL[lane * XP + c0 + c]) =
            make_float4(acc[c], acc[c + 1], acc[c + 2], acc[c + 3]);
    __syncthreads();
    {
        for (int i = tid; i < 64 * 16; i += 256) {
            int r = i >> 4, c4 = i & 15;
            if (base + r < n) {
                const float* f = &xsL[r * XP + c4 * 4];
                __half2 a = __floats2half2_rn(f[0], f[1]);
                __half2 b2 = __floats2half2_rn(f[2], f[3]);
                uint2 u;
                u.x = *reinterpret_cast<unsigned int*>(&a);
                u.y = *reinterpret_cast<unsigned int*>(&b2);
                *reinterpret_cast<uint2*>(xs + (size_t)(base + r) * DD + c4 * 4) = u;
            }
        }
    }
}

// one wave per destination node, single pass (shift-invariant softmax, no max).
// xs gathered as fp16 rows (128 B) -> half the L2/L3 traffic.
__global__ __launch_bounds__(256) void agg_k(
    const int* __restrict__ rowstart, const int* __restrict__ csr_src,
    const __half* __restrict__ xs, const float* __restrict__ es,
    const float* __restrict__ ed, const float* __restrict__ bias,
    float* __restrict__ hout, int n, int relu) {
    int wid = (blockIdx.x * blockDim.x + threadIdx.x) >> 6;
    int lane = threadIdx.x & 63;
    if (wid >= n) return;
    int beg = rowstart[wid];
    int deg = rowstart[wid + 1] - beg;
    float edv = ed[wid];
    int slot = lane >> 4;
    int fl = lane & 15;

    float4 acc = make_float4(0.f, 0.f, 0.f, 0.f);
    float zl = 0.f;

    for (int c0 = 0; c0 < deg; c0 += 64) {
        int rem = min(64, deg - c0);
        int sv = 0;
        float pv = 0.f;
        if (lane < rem) {
            sv = csr_src[beg + c0 + lane];
            float e = es[sv] + edv;
            e = (e >= 0.f) ? e : NEG_SLOPE * e;
            pv = __expf(e);
        }
        zl += pv;
        int iters = (rem + 3) >> 2;
        for (int c = 0; c < iters; ++c) {
            int j = c * 4 + slot;
            float p = __shfl(pv, j, 64);
            int s = __shfl(sv, j, 64);
            uint2 u = *reinterpret_cast<const uint2*>(xs + (size_t)s * DD + fl * 4);
            float2 f01 = __half22float2(*reinterpret_cast<__half2*>(&u.x));
            float2 f23 = __half22float2(*reinterpret_cast<__half2*>(&u.y));
            acc.x = fmaf(p, f01.x, acc.x);
            acc.y = fmaf(p, f01.y, acc.y);
            acc.z = fmaf(p, f23.x, acc.z);
            acc.w = fmaf(p, f23.y, acc.w);
        }
    }

#pragma unroll
    for (int off = 32; off; off >>= 1) zl += __shfl_xor(zl, off, 64);
    acc.x += __shfl_xor(acc.x, 16, 64); acc.y += __shfl_xor(acc.y, 16, 64);
    acc.z += __shfl_xor(acc.z, 16, 64); acc.w += __shfl_xor(acc.w, 16, 64);
    acc.x += __shfl_xor(acc.x, 32, 64); acc.y += __shfl_xor(acc.y, 32, 64);
    acc.z += __shfl_xor(acc.z, 32, 64); acc.w += __shfl_xor(acc.w, 32, 64);

    float inv = 1.f / (zl + EPSV);
    float4 b4 = reinterpret_cast<const float4*>(bias)[fl];
    float4 val;
    val.x = fmaf(acc.x, inv, b4.x);
    val.y = fmaf(acc.y, inv, b4.y);
    val.z = fmaf(acc.z, inv, b4.z);
    val.w = fmaf(acc.w, inv, b4.w);
    if (relu) {
        val.x = fmaxf(val.x, 0.f); val.y = fmaxf(val.y, 0.f);
        val.z = fmaxf(val.z, 0.f); val.w = fmaxf(val.w, 0.f);
    }
    if (slot == 0)
        *reinterpret_cast<float4*>(hout + (size_t)wid * DD + fl * 4) = val;
}

// ---------------- pooling + final linear ----------------

// one wave handles 16 consecutive (batch-sorted) nodes; run-length flush
__global__ __launch_bounds__(256) void pool_k(
    const float* __restrict__ h, const int* __restrict__ batch,
    float* __restrict__ psum, int n) {
    int wid = (blockIdx.x * blockDim.x + threadIdx.x) >> 6;
    int lane = threadIdx.x & 63;
    int beg = wid * 16;
    if (beg >= n) return;
    int end = min(beg + 16, n);
    int curg = batch[beg];
    float acc = 0.f;
    for (int i = beg; i < end; ++i) {
        int g = batch[i];
        if (g != curg) {
            atomicAdd(&psum[curg * DD + lane], acc);
            acc = 0.f; curg = g;
        }
        acc += h[(size_t)i * DD + lane];
    }
    atomicAdd(&psum[curg * DD + lane], acc);
}

// final linear; per-graph counts from binary search on sorted batch
__global__ void final_k(const float* __restrict__ psum, const int* __restrict__ batch,
                        const float* __restrict__ post_emb,
                        const float* __restrict__ lin_w, const float* __restrict__ lin_b,
                        float* __restrict__ out) {
    __shared__ int sL[GG + 1];
    int r = threadIdx.x;
    if (r <= GG) {
        int lo = 0, hi = NN;
        while (lo < hi) {
            int m = (lo + hi) >> 1;
            if (batch[m] < r) lo = m + 1; else hi = m;
        }
        sL[r] = lo;
    }
    __syncthreads();
    if (r >= 2 * GG) return;
    float o0 = 0.f, o1 = 0.f;
    if (r < GG) {
        float c = fmaxf((float)(sL[r + 1] - sL[r]), 1.f);
        float inv = 1.f / c;
        for (int d2 = 0; d2 < DD; ++d2) {
            float v = psum[r * DD + d2] * inv;
            o0 = fmaf(v, lin_w[d2 * 2 + 0], o0);
            o1 = fmaf(v, lin_w[d2 * 2 + 1], o1);
        }
    } else {
        const float* pe = post_emb + (size_t)(r - GG) * DD;
        for (int d2 = 0; d2 < DD; ++d2) {
            float v = pe[d2];
            o0 = fmaf(v, lin_w[d2 * 2 + 0], o0);
            o1 = fmaf(v, lin_w[d2 * 2 + 1], o1);
        }
    }
    out[r * 2 + 0] = o0 + lin_b[0];
    out[r * 2 + 1] = o1 + lin_b[1];
}

// ---------------- host ----------------

extern "C" void kernel_launch(void* const* d_in, const int* in_sizes, int n_in,
                              void* d_out, int out_size, void* d_ws, size_t ws_size,
                              hipStream_t stream) {
    const float* x        = (const float*)d_in[0];
    const int*   ei       = (const int*)d_in[1];
    const int*   src      = ei;
    const int*   dst      = ei + EE;
    const int*   batch    = (const int*)d_in[2];
    const float* post_emb = (const float*)d_in[3];
    const float* Ws[3] = {(const float*)d_in[4],  (const float*)d_in[9],  (const float*)d_in[14]};
    const float* Wd[3] = {(const float*)d_in[5],  (const float*)d_in[10], (const float*)d_in[15]};
    const float* av[3] = {(const float*)d_in[6],  (const float*)d_in[11], (const float*)d_in[16]};
    const float* ad[3] = {(const float*)d_in[7],  (const float*)d_in[12], (const float*)d_in[17]};
    const float* bb[3] = {(const float*)d_in[8],  (const float*)d_in[13], (const float*)d_in[18]};
    const float* lin_w = (const float*)d_in[19];
    const float* lin_b = (const float*)d_in[20];
    float* outp = (float*)d_out;

    char* w = (char*)d_ws;
    size_t off = 0;
    auto alloc = [&](size_t bytes) -> char* {
        char* p = w + off;
        off += (bytes + 255) & ~(size_t)255;
        return p;
    };
    __half*       xs       = (__half*)alloc((size_t)NN * DD * 2);
    float*        h        = (float*)alloc((size_t)NN * DD * 4);
    float*        es       = (float*)alloc((size_t)NN * 4);
    float*        ed       = (float*)alloc((size_t)NN * 4);
    int*          rowstart = (int*)alloc((size_t)(NN + 1) * 4);
    int*          csr      = (int*)alloc((size_t)EE * 4);
    float*        wdadAll  = (float*)alloc(3 * FF * 4);
    float*        wsasAll  = (float*)alloc(3 * FF * 4);
    float*        psum     = (float*)alloc((size_t)GG * DD * 4);
    unsigned int* gbuf     = (unsigned int*)alloc((size_t)NBKT * BCAP * 4);
    int*          gcur     = (int*)alloc(256 * 4);
    int*          bktoff   = (int*)alloc(256 * 4);

    // ---- CSR build: bin -> bucket-prefix -> merged build ----
    hipMemsetAsync(gcur, 0, 256 * 4, stream);
    hipMemsetAsync(psum, 0, (size_t)GG * DD * 4, stream);
    bin_k<<<NCH, 256, 0, stream>>>(src, dst, gbuf, gcur);
    bpre_k<<<1, 256, 0, stream>>>(gcur, bktoff, rowstart);
    build_k<<<NBKT, 256, 0, stream>>>(gbuf, gcur, bktoff, rowstart, csr);

    // ---- per-layer projection vectors ----
    vecs3_k<<<3, 128, 0, stream>>>(Wd[0], ad[0], Ws[0], av[0],
                                   Wd[1], ad[1], Ws[1], av[1],
                                   Wd[2], ad[2], Ws[2], av[2], wdadAll, wsasAll);

    // ---- 3 GAT layers ----
    const int XB = (NN + 63) / 64;        // 782 blocks: 64 rows per block
    const float* hin = x;
    for (int l = 0; l < 3; ++l) {
        if (l == 0)
            xform_k<FF><<<XB, 256, 0, stream>>>(hin, Ws[l], wsasAll + l * FF,
                                                wdadAll + l * FF, xs, es, ed, NN);
        else
            xform_k<DD><<<XB, 256, 0, stream>>>(hin, Ws[l], wsasAll + l * FF,
                                                wdadAll + l * FF, xs, es, ed, NN);
        agg_k<<<(NN * 64 + 255) / 256, 256, 0, stream>>>(rowstart, csr, xs, es, ed,
                                                         bb[l], h, NN, (l < 2) ? 1 : 0);
        hin = h;
    }

    // ---- pooling + final linear ----
    pool_k<<<((NN + 15) / 16 * 64 + 255) / 256, 256, 0, stream>>>(h, batch, psum, NN);
    final_k<<<1, 128, 0, stream>>>(psum, batch, post_emb, lin_w, lin_b, outp);
}